// Round 1
// baseline (2984.841 us; speedup 1.0000x reference)
//
#include <hip/hip_runtime.h>

#define FDIM 128

// ---------------- degree ----------------
__global__ void k_deg_init(int* __restrict__ deg, int n) {
    int i = blockIdx.x * blockDim.x + threadIdx.x;
    if (i < n) deg[i] = 1;  // self-loop
}

__global__ void k_deg_count(const int* __restrict__ dst, int* __restrict__ deg, int e) {
    int i = blockIdx.x * blockDim.x + threadIdx.x;
    if (i < e) atomicAdd(&deg[dst[i]], 1);
}

__global__ void k_dinv(const int* __restrict__ deg, float* __restrict__ dinv, int n) {
    int i = blockIdx.x * blockDim.x + threadIdx.x;
    if (i < n) dinv[i] = rsqrtf((float)deg[i]);
}

// ---------------- h = x @ W, scaled by dinv[row]; writes hs (scratch) and
// out (accumulator init = self-loop message) ----------------
// Block: 256 threads, 128 rows per block. W (128x128 fp32 = 64 KB) staged in LDS.
// Each 32-thread group handles one row; thread computes 4 consecutive cols.
__global__ __launch_bounds__(256) void k_gemm(
    const float* __restrict__ x, const float* __restrict__ W,
    const float* __restrict__ dinv, float* __restrict__ hs,
    float* __restrict__ out, int n) {
    __shared__ float4 Ws4[FDIM * (FDIM / 4)];  // 64 KB
    const float4* W4 = (const float4*)W;
    for (int i = threadIdx.x; i < FDIM * FDIM / 4; i += 256) Ws4[i] = W4[i];
    __syncthreads();

    const int c4 = threadIdx.x & 31;       // col chunk (4 floats)
    const int rsub = threadIdx.x >> 5;     // 0..7
    const int base = blockIdx.x * 128;

    for (int it = 0; it < 16; ++it) {
        int row = base + it * 8 + rsub;
        if (row >= n) return;  // no further syncs
        const float4* xr4 = (const float4*)(x + (size_t)row * FDIM);
        float4 acc = make_float4(0.f, 0.f, 0.f, 0.f);
        #pragma unroll 8
        for (int k4 = 0; k4 < FDIM / 4; ++k4) {
            float4 xv = xr4[k4];
            float4 w0 = Ws4[(k4 * 4 + 0) * 32 + c4];
            float4 w1 = Ws4[(k4 * 4 + 1) * 32 + c4];
            float4 w2 = Ws4[(k4 * 4 + 2) * 32 + c4];
            float4 w3 = Ws4[(k4 * 4 + 3) * 32 + c4];
            acc.x += xv.x * w0.x + xv.y * w1.x + xv.z * w2.x + xv.w * w3.x;
            acc.y += xv.x * w0.y + xv.y * w1.y + xv.z * w2.y + xv.w * w3.y;
            acc.z += xv.x * w0.z + xv.y * w1.z + xv.z * w2.z + xv.w * w3.z;
            acc.w += xv.x * w0.w + xv.y * w1.w + xv.z * w2.w + xv.w * w3.w;
        }
        float s = dinv[row];
        float4 r = make_float4(acc.x * s, acc.y * s, acc.z * s, acc.w * s);
        ((float4*)(hs + (size_t)row * FDIM))[c4] = r;
        ((float4*)(out + (size_t)row * FDIM))[c4] = r;  // acc init = self-loop term
    }
}

// ---------------- edge scatter: out[dst] += hs[src] ----------------
// One thread per (edge, 4-float chunk): E*32 threads.
__global__ void k_scatter(const int* __restrict__ src, const int* __restrict__ dst,
                          const float* __restrict__ hs, float* __restrict__ out, int e) {
    int t = blockIdx.x * blockDim.x + threadIdx.x;
    int ed = t >> 5;
    if (ed >= e) return;
    int c4 = t & 31;
    int s = src[ed];
    int d = dst[ed];
    float4 v = ((const float4*)(hs + (size_t)s * FDIM))[c4];
    float* o = out + (size_t)d * FDIM + c4 * 4;
    unsafeAtomicAdd(o + 0, v.x);
    unsafeAtomicAdd(o + 1, v.y);
    unsafeAtomicAdd(o + 2, v.z);
    unsafeAtomicAdd(o + 3, v.w);
}

// ---------------- epilogue: out = out * dinv + b ----------------
__global__ void k_final(float* __restrict__ out, const float* __restrict__ dinv,
                        const float* __restrict__ b, int n) {
    int t = blockIdx.x * blockDim.x + threadIdx.x;
    int i = t >> 5;
    if (i >= n) return;
    int c4 = t & 31;
    float4 v = ((float4*)(out + (size_t)i * FDIM))[c4];
    float s = dinv[i];
    float4 bb = ((const float4*)b)[c4];
    v.x = v.x * s + bb.x;
    v.y = v.y * s + bb.y;
    v.z = v.z * s + bb.z;
    v.w = v.w * s + bb.w;
    ((float4*)(out + (size_t)i * FDIM))[c4] = v;
}

extern "C" void kernel_launch(void* const* d_in, const int* in_sizes, int n_in,
                              void* d_out, int out_size, void* d_ws, size_t ws_size,
                              hipStream_t stream) {
    const float* x  = (const float*)d_in[0];
    const int*   ei = (const int*)d_in[1];     // [2, E] int32
    const float* W  = (const float*)d_in[2];
    const float* b  = (const float*)d_in[3];

    const int n = in_sizes[0] / FDIM;
    const int e = in_sizes[1] / 2;
    const int* src = ei;
    const int* dst = ei + e;
    float* out = (float*)d_out;

    // workspace layout: deg (n int) | dinv (n float) | hs (n*128 float)
    char* ws = (char*)d_ws;
    size_t off = 0;
    int* deg = (int*)(ws + off);           off += ((size_t)n * 4 + 511) & ~(size_t)511;
    float* dinv = (float*)(ws + off);      off += ((size_t)n * 4 + 511) & ~(size_t)511;
    float* hs = (float*)(ws + off);        // n*128 floats

    k_deg_init<<<(n + 255) / 256, 256, 0, stream>>>(deg, n);
    k_deg_count<<<(e + 255) / 256, 256, 0, stream>>>(dst, deg, e);
    k_dinv<<<(n + 255) / 256, 256, 0, stream>>>(deg, dinv, n);
    k_gemm<<<(n + 127) / 128, 256, 0, stream>>>(x, W, dinv, hs, out, n);
    {
        long long threads = (long long)e * 32;
        int blocks = (int)((threads + 255) / 256);
        k_scatter<<<blocks, 256, 0, stream>>>(src, dst, hs, out, e);
    }
    {
        long long threads = (long long)n * 32;
        int blocks = (int)((threads + 255) / 256);
        k_final<<<blocks, 256, 0, stream>>>(out, dinv, b, n);
    }
}

// Round 2
// 540.945 us; speedup vs baseline: 5.5178x; 5.5178x over previous
//
#include <hip/hip_runtime.h>

#define FDIM 128
#define CHUNK 1024

// ---------------- degree ----------------
__global__ void k_deg_init(int* __restrict__ deg, int n) {
    int i = blockIdx.x * blockDim.x + threadIdx.x;
    if (i < n) deg[i] = 1;  // self-loop
}

__global__ void k_deg_count(const int* __restrict__ dst, int* __restrict__ deg, int e) {
    int i = blockIdx.x * blockDim.x + threadIdx.x;
    if (i < e) atomicAdd(&deg[dst[i]], 1);
}

__global__ void k_dinv(const int* __restrict__ deg, float* __restrict__ dinv, int n) {
    int i = blockIdx.x * blockDim.x + threadIdx.x;
    if (i < n) dinv[i] = rsqrtf((float)deg[i]);
}

// ---------------- exclusive scan of (deg-1) -> row_start ----------------
__global__ __launch_bounds__(256) void k_scan_a(const int* __restrict__ deg, int* __restrict__ csum, int n) {
    int base = blockIdx.x * CHUNK;
    int s = 0;
    for (int k = threadIdx.x; k < CHUNK; k += 256) {
        int idx = base + k;
        if (idx < n) s += deg[idx] - 1;
    }
    __shared__ int red[256];
    red[threadIdx.x] = s;
    __syncthreads();
    for (int off = 128; off > 0; off >>= 1) {
        if (threadIdx.x < off) red[threadIdx.x] += red[threadIdx.x + off];
        __syncthreads();
    }
    if (threadIdx.x == 0) csum[blockIdx.x] = red[0];
}

__global__ void k_scan_b(int* __restrict__ csum, int nch) {
    if (threadIdx.x == 0 && blockIdx.x == 0) {
        int run = 0;
        for (int c = 0; c < nch; ++c) {
            int v = csum[c];
            csum[c] = run;
            run += v;
        }
    }
}

__global__ __launch_bounds__(256) void k_scan_c(const int* __restrict__ deg, const int* __restrict__ csum,
                                                int* __restrict__ row_start, int* __restrict__ cursor, int n) {
    int base = blockIdx.x * CHUNK + threadIdx.x * 4;
    int v[4];
    int s = 0;
    #pragma unroll
    for (int k = 0; k < 4; ++k) {
        v[k] = (base + k < n) ? (deg[base + k] - 1) : 0;
        s += v[k];
    }
    __shared__ int tsum[256];
    tsum[threadIdx.x] = s;
    __syncthreads();
    // Hillis-Steele inclusive scan
    for (int off = 1; off < 256; off <<= 1) {
        int t = (threadIdx.x >= off) ? tsum[threadIdx.x - off] : 0;
        __syncthreads();
        tsum[threadIdx.x] += t;
        __syncthreads();
    }
    int run = (threadIdx.x ? tsum[threadIdx.x - 1] : 0) + csum[blockIdx.x];
    #pragma unroll
    for (int k = 0; k < 4; ++k) {
        if (base + k < n) {
            row_start[base + k] = run;
            cursor[base + k] = run;
            run += v[k];
        }
    }
}

// ---------------- bin edges by dst: ebuf[bucket(dst)] = src ----------------
__global__ void k_bin(const int* __restrict__ src, const int* __restrict__ dst,
                      int* __restrict__ cursor, int* __restrict__ ebuf, int e) {
    int i = blockIdx.x * blockDim.x + threadIdx.x;
    if (i < e) {
        int d = dst[i];
        int p = atomicAdd(&cursor[d], 1);
        ebuf[p] = src[i];
    }
}

// ---------------- h = x @ W, scaled by dinv[row] -> hs ----------------
__global__ __launch_bounds__(256) void k_gemm(
    const float* __restrict__ x, const float* __restrict__ W,
    const float* __restrict__ dinv, float* __restrict__ hs, int n) {
    __shared__ float4 Ws4[FDIM * (FDIM / 4)];  // 64 KB
    const float4* W4 = (const float4*)W;
    for (int i = threadIdx.x; i < FDIM * FDIM / 4; i += 256) Ws4[i] = W4[i];
    __syncthreads();

    const int c4 = threadIdx.x & 31;       // col chunk (4 floats)
    const int rsub = threadIdx.x >> 5;     // 0..7
    const int base = blockIdx.x * 128;

    for (int it = 0; it < 16; ++it) {
        int row = base + it * 8 + rsub;
        if (row >= n) return;  // no further syncs
        const float4* xr4 = (const float4*)(x + (size_t)row * FDIM);
        float4 acc = make_float4(0.f, 0.f, 0.f, 0.f);
        #pragma unroll 8
        for (int k4 = 0; k4 < FDIM / 4; ++k4) {
            float4 xv = xr4[k4];
            float4 w0 = Ws4[(k4 * 4 + 0) * 32 + c4];
            float4 w1 = Ws4[(k4 * 4 + 1) * 32 + c4];
            float4 w2 = Ws4[(k4 * 4 + 2) * 32 + c4];
            float4 w3 = Ws4[(k4 * 4 + 3) * 32 + c4];
            acc.x += xv.x * w0.x + xv.y * w1.x + xv.z * w2.x + xv.w * w3.x;
            acc.y += xv.x * w0.y + xv.y * w1.y + xv.z * w2.y + xv.w * w3.y;
            acc.z += xv.x * w0.z + xv.y * w1.z + xv.z * w2.z + xv.w * w3.z;
            acc.w += xv.x * w0.w + xv.y * w1.w + xv.z * w2.w + xv.w * w3.w;
        }
        float s = dinv[row];
        float4 r = make_float4(acc.x * s, acc.y * s, acc.z * s, acc.w * s);
        ((float4*)(hs + (size_t)row * FDIM))[c4] = r;
    }
}

// ---------------- gather: out[i] = dinv[i]*(hs[i] + sum_{e->i} hs[src]) + b ----------------
// One wave (64 lanes) per node; lane holds float2 (128 floats/row).
__global__ __launch_bounds__(256) void k_gather(
    const float* __restrict__ hs, const int* __restrict__ ebuf,
    const int* __restrict__ row_start, const int* __restrict__ deg,
    const float* __restrict__ dinv, const float* __restrict__ bias,
    float* __restrict__ out, int n) {
    int i = blockIdx.x * 4 + (threadIdx.x >> 6);  // node = global wave id
    if (i >= n) return;
    int lane = threadIdx.x & 63;

    int beg = row_start[i];
    int cnt = deg[i] - 1;
    int end = beg + cnt;

    float2 acc = ((const float2*)(hs + (size_t)i * FDIM))[lane];  // self-loop term

    int j = beg;
    for (; j + 1 < end; j += 2) {
        int s0 = ebuf[j];
        int s1 = ebuf[j + 1];
        float2 v0 = ((const float2*)(hs + (size_t)s0 * FDIM))[lane];
        float2 v1 = ((const float2*)(hs + (size_t)s1 * FDIM))[lane];
        acc.x += v0.x + v1.x;
        acc.y += v0.y + v1.y;
    }
    if (j < end) {
        int s0 = ebuf[j];
        float2 v0 = ((const float2*)(hs + (size_t)s0 * FDIM))[lane];
        acc.x += v0.x;
        acc.y += v0.y;
    }

    float sc = dinv[i];
    float2 bb = ((const float2*)bias)[lane];
    float2 r = make_float2(acc.x * sc + bb.x, acc.y * sc + bb.y);
    ((float2*)(out + (size_t)i * FDIM))[lane] = r;
}

extern "C" void kernel_launch(void* const* d_in, const int* in_sizes, int n_in,
                              void* d_out, int out_size, void* d_ws, size_t ws_size,
                              hipStream_t stream) {
    const float* x  = (const float*)d_in[0];
    const int*   ei = (const int*)d_in[1];     // [2, E] int32
    const float* W  = (const float*)d_in[2];
    const float* b  = (const float*)d_in[3];

    const int n = in_sizes[0] / FDIM;
    const int e = in_sizes[1] / 2;
    const int* src = ei;
    const int* dst = ei + e;
    float* out = (float*)d_out;

    const int nch = (n + CHUNK - 1) / CHUNK;

    // workspace layout
    char* ws = (char*)d_ws;
    size_t off = 0;
    auto alloc = [&](size_t bytes) {
        char* p = ws + off;
        off += (bytes + 511) & ~(size_t)511;
        return p;
    };
    int*   deg       = (int*)alloc((size_t)n * 4);
    float* dinv      = (float*)alloc((size_t)n * 4);
    int*   row_start = (int*)alloc((size_t)n * 4);
    int*   cursor    = (int*)alloc((size_t)n * 4);
    int*   csum      = (int*)alloc((size_t)nch * 4);
    int*   ebuf      = (int*)alloc((size_t)e * 4);
    float* hs        = (float*)alloc((size_t)n * FDIM * 4);

    k_deg_init<<<(n + 255) / 256, 256, 0, stream>>>(deg, n);
    k_deg_count<<<(e + 255) / 256, 256, 0, stream>>>(dst, deg, e);
    k_dinv<<<(n + 255) / 256, 256, 0, stream>>>(deg, dinv, n);

    k_scan_a<<<nch, 256, 0, stream>>>(deg, csum, n);
    k_scan_b<<<1, 64, 0, stream>>>(csum, nch);
    k_scan_c<<<nch, 256, 0, stream>>>(deg, csum, row_start, cursor, n);

    k_gemm<<<(n + 127) / 128, 256, 0, stream>>>(x, W, dinv, hs, n);
    k_bin<<<(e + 255) / 256, 256, 0, stream>>>(src, dst, cursor, ebuf, e);

    {
        int blocks = (n + 3) / 4;  // 4 waves (nodes) per 256-thread block
        k_gather<<<blocks, 256, 0, stream>>>(hs, ebuf, row_start, deg, dinv, b, out, n);
    }
}

// Round 3
// 431.454 us; speedup vs baseline: 6.9181x; 1.2538x over previous
//
#include <hip/hip_runtime.h>

#define FDIM 128
#define CHUNK 1024

__device__ __forceinline__ unsigned short f2bf(float f) {
    unsigned int u = __float_as_uint(f);
    unsigned int r = u + 0x7fffu + ((u >> 16) & 1u);  // RNE
    return (unsigned short)(r >> 16);
}

// ---------------- degree ----------------
__global__ void k_deg_init(int* __restrict__ deg, int n) {
    int i = blockIdx.x * blockDim.x + threadIdx.x;
    if (i < n) deg[i] = 1;  // self-loop
}

__global__ void k_deg_count(const int* __restrict__ dst, int* __restrict__ deg, int e) {
    int i = blockIdx.x * blockDim.x + threadIdx.x;
    if (i < e) atomicAdd(&deg[dst[i]], 1);
}

__global__ void k_dinv(const int* __restrict__ deg, float* __restrict__ dinv, int n) {
    int i = blockIdx.x * blockDim.x + threadIdx.x;
    if (i < n) dinv[i] = rsqrtf((float)deg[i]);
}

// ---------------- exclusive scan of (deg-1) -> row_start ----------------
__global__ __launch_bounds__(256) void k_scan_a(const int* __restrict__ deg, int* __restrict__ csum, int n) {
    int base = blockIdx.x * CHUNK;
    int s = 0;
    for (int k = threadIdx.x; k < CHUNK; k += 256) {
        int idx = base + k;
        if (idx < n) s += deg[idx] - 1;
    }
    __shared__ int red[256];
    red[threadIdx.x] = s;
    __syncthreads();
    for (int off = 128; off > 0; off >>= 1) {
        if (threadIdx.x < off) red[threadIdx.x] += red[threadIdx.x + off];
        __syncthreads();
    }
    if (threadIdx.x == 0) csum[blockIdx.x] = red[0];
}

__global__ void k_scan_b(int* __restrict__ csum, int nch) {
    if (threadIdx.x == 0 && blockIdx.x == 0) {
        int run = 0;
        for (int c = 0; c < nch; ++c) {
            int v = csum[c];
            csum[c] = run;
            run += v;
        }
    }
}

__global__ __launch_bounds__(256) void k_scan_c(const int* __restrict__ deg, const int* __restrict__ csum,
                                                int* __restrict__ row_start, int* __restrict__ cursor, int n) {
    int base = blockIdx.x * CHUNK + threadIdx.x * 4;
    int v[4];
    int s = 0;
    #pragma unroll
    for (int k = 0; k < 4; ++k) {
        v[k] = (base + k < n) ? (deg[base + k] - 1) : 0;
        s += v[k];
    }
    __shared__ int tsum[256];
    tsum[threadIdx.x] = s;
    __syncthreads();
    for (int off = 1; off < 256; off <<= 1) {
        int t = (threadIdx.x >= off) ? tsum[threadIdx.x - off] : 0;
        __syncthreads();
        tsum[threadIdx.x] += t;
        __syncthreads();
    }
    int run = (threadIdx.x ? tsum[threadIdx.x - 1] : 0) + csum[blockIdx.x];
    #pragma unroll
    for (int k = 0; k < 4; ++k) {
        if (base + k < n) {
            row_start[base + k] = run;
            cursor[base + k] = run;
            run += v[k];
        }
    }
}

// ---------------- bin edges by dst ----------------
__global__ void k_bin(const int* __restrict__ src, const int* __restrict__ dst,
                      int* __restrict__ cursor, int* __restrict__ ebuf, int e) {
    int i = blockIdx.x * blockDim.x + threadIdx.x;
    if (i < e) {
        int d = dst[i];
        int p = atomicAdd(&cursor[d], 1);
        ebuf[p] = src[i];
    }
}

// ---------------- hs = bf16((x @ W) * dinv[row]) ----------------
// 256 threads; block computes 128 rows x 128 cols. Thread micro-tile:
// 8 rows x 8 cols (cols {4cg..4cg+3} and {64+4cg..64+4cg+3}).
// W in LDS (64 KB, 2 blocks/CU); x via global broadcast loads (L1-resident).
__global__ __launch_bounds__(256) void k_gemm(
    const float* __restrict__ x, const float* __restrict__ W,
    const float* __restrict__ dinv, unsigned short* __restrict__ hs, int n) {
    __shared__ float Ws[FDIM * FDIM];  // 64 KB, row-major [k][c]
    {
        const float4* W4 = (const float4*)W;
        float4* Wl = (float4*)Ws;
        for (int i = threadIdx.x; i < FDIM * FDIM / 4; i += 256) Wl[i] = W4[i];
    }
    __syncthreads();

    const int cg = threadIdx.x & 15;   // col group
    const int rg = threadIdx.x >> 4;   // row group (0..15)
    const int row0 = blockIdx.x * 128 + rg * 8;
    const float4* Ws4 = (const float4*)Ws;

    // clamped row pointers (last block tail)
    const float4* xp[8];
    #pragma unroll
    for (int r = 0; r < 8; ++r) {
        int rc = row0 + r;
        if (rc >= n) rc = n - 1;
        xp[r] = (const float4*)(x + (size_t)rc * FDIM);
    }

    float4 acc[8][2];
    #pragma unroll
    for (int r = 0; r < 8; ++r) {
        acc[r][0] = make_float4(0.f, 0.f, 0.f, 0.f);
        acc[r][1] = make_float4(0.f, 0.f, 0.f, 0.f);
    }

    #pragma unroll 2
    for (int k4 = 0; k4 < FDIM / 4; ++k4) {
        float4 xv[8];
        #pragma unroll
        for (int r = 0; r < 8; ++r) xv[r] = xp[r][k4];
        #pragma unroll
        for (int kk = 0; kk < 4; ++kk) {
            float4 w0 = Ws4[(k4 * 4 + kk) * 32 + cg];        // cols 4cg..4cg+3
            float4 w1 = Ws4[(k4 * 4 + kk) * 32 + 16 + cg];   // cols 64+4cg..
            #pragma unroll
            for (int r = 0; r < 8; ++r) {
                float xs = (kk == 0) ? xv[r].x : (kk == 1) ? xv[r].y : (kk == 2) ? xv[r].z : xv[r].w;
                acc[r][0].x += xs * w0.x;
                acc[r][0].y += xs * w0.y;
                acc[r][0].z += xs * w0.z;
                acc[r][0].w += xs * w0.w;
                acc[r][1].x += xs * w1.x;
                acc[r][1].y += xs * w1.y;
                acc[r][1].z += xs * w1.z;
                acc[r][1].w += xs * w1.w;
            }
        }
    }

    #pragma unroll
    for (int r = 0; r < 8; ++r) {
        int row = row0 + r;
        if (row >= n) break;
        float s = dinv[row];
        ushort4 p0, p1;
        p0.x = f2bf(acc[r][0].x * s);
        p0.y = f2bf(acc[r][0].y * s);
        p0.z = f2bf(acc[r][0].z * s);
        p0.w = f2bf(acc[r][0].w * s);
        p1.x = f2bf(acc[r][1].x * s);
        p1.y = f2bf(acc[r][1].y * s);
        p1.z = f2bf(acc[r][1].z * s);
        p1.w = f2bf(acc[r][1].w * s);
        *(ushort4*)(hs + (size_t)row * FDIM + cg * 4) = p0;
        *(ushort4*)(hs + (size_t)row * FDIM + 64 + cg * 4) = p1;
    }
}

// ---------------- gather: out[i] = dinv[i]*(hs[i] + sum hs[src]) + b ----------------
// One wave per node; lane holds 2 bf16 (4 B) of the 128-wide row.
__global__ __launch_bounds__(256) void k_gather(
    const unsigned short* __restrict__ hs, const int* __restrict__ ebuf,
    const int* __restrict__ row_start, const int* __restrict__ deg,
    const float* __restrict__ dinv, const float* __restrict__ bias,
    float* __restrict__ out, int n) {
    int i = blockIdx.x * 4 + (threadIdx.x >> 6);
    if (i >= n) return;
    int lane = threadIdx.x & 63;

    int beg = row_start[i];
    int cnt = deg[i] - 1;
    int end = beg + cnt;

    unsigned int u = ((const unsigned int*)(hs + (size_t)i * FDIM))[lane];
    float ax = __uint_as_float(u << 16);
    float ay = __uint_as_float(u & 0xffff0000u);

    int j = beg;
    for (; j + 3 < end; j += 4) {
        int s0 = ebuf[j], s1 = ebuf[j + 1], s2 = ebuf[j + 2], s3 = ebuf[j + 3];
        unsigned int u0 = ((const unsigned int*)(hs + (size_t)s0 * FDIM))[lane];
        unsigned int u1 = ((const unsigned int*)(hs + (size_t)s1 * FDIM))[lane];
        unsigned int u2 = ((const unsigned int*)(hs + (size_t)s2 * FDIM))[lane];
        unsigned int u3 = ((const unsigned int*)(hs + (size_t)s3 * FDIM))[lane];
        ax += __uint_as_float(u0 << 16) + __uint_as_float(u1 << 16)
            + __uint_as_float(u2 << 16) + __uint_as_float(u3 << 16);
        ay += __uint_as_float(u0 & 0xffff0000u) + __uint_as_float(u1 & 0xffff0000u)
            + __uint_as_float(u2 & 0xffff0000u) + __uint_as_float(u3 & 0xffff0000u);
    }
    for (; j < end; ++j) {
        int s0 = ebuf[j];
        unsigned int u0 = ((const unsigned int*)(hs + (size_t)s0 * FDIM))[lane];
        ax += __uint_as_float(u0 << 16);
        ay += __uint_as_float(u0 & 0xffff0000u);
    }

    float sc = dinv[i];
    float2 bb = ((const float2*)bias)[lane];
    float2 r = make_float2(ax * sc + bb.x, ay * sc + bb.y);
    ((float2*)(out + (size_t)i * FDIM))[lane] = r;
}

extern "C" void kernel_launch(void* const* d_in, const int* in_sizes, int n_in,
                              void* d_out, int out_size, void* d_ws, size_t ws_size,
                              hipStream_t stream) {
    const float* x  = (const float*)d_in[0];
    const int*   ei = (const int*)d_in[1];     // [2, E] int32
    const float* W  = (const float*)d_in[2];
    const float* b  = (const float*)d_in[3];

    const int n = in_sizes[0] / FDIM;
    const int e = in_sizes[1] / 2;
    const int* src = ei;
    const int* dst = ei + e;
    float* out = (float*)d_out;

    const int nch = (n + CHUNK - 1) / CHUNK;

    char* ws = (char*)d_ws;
    size_t off = 0;
    auto alloc = [&](size_t bytes) {
        char* p = ws + off;
        off += (bytes + 511) & ~(size_t)511;
        return p;
    };
    int*            deg       = (int*)alloc((size_t)n * 4);
    float*          dinv      = (float*)alloc((size_t)n * 4);
    int*            row_start = (int*)alloc((size_t)n * 4);
    int*            cursor    = (int*)alloc((size_t)n * 4);
    int*            csum      = (int*)alloc((size_t)nch * 4);
    int*            ebuf      = (int*)alloc((size_t)e * 4);
    unsigned short* hs        = (unsigned short*)alloc((size_t)n * FDIM * 2);

    k_deg_init<<<(n + 255) / 256, 256, 0, stream>>>(deg, n);
    k_deg_count<<<(e + 255) / 256, 256, 0, stream>>>(dst, deg, e);
    k_dinv<<<(n + 255) / 256, 256, 0, stream>>>(deg, dinv, n);

    k_scan_a<<<nch, 256, 0, stream>>>(deg, csum, n);
    k_scan_b<<<1, 64, 0, stream>>>(csum, nch);
    k_scan_c<<<nch, 256, 0, stream>>>(deg, csum, row_start, cursor, n);

    k_gemm<<<(n + 127) / 128, 256, 0, stream>>>(x, W, dinv, hs, n);
    k_bin<<<(e + 255) / 256, 256, 0, stream>>>(src, dst, cursor, ebuf, e);

    {
        int blocks = (n + 3) / 4;
        k_gather<<<blocks, 256, 0, stream>>>(hs, ebuf, row_start, deg, dinv, b, out, n);
    }
}

// Round 4
// 294.541 us; speedup vs baseline: 10.1339x; 1.4648x over previous
//
#include <hip/hip_runtime.h>

#define FDIM 128
#define CHUNK 1024
#define NBMAX 512   // coarse buckets (dst>>8); supports n <= 131072
#define EPB 4096    // edges per block in hist/scatter phases

__device__ __forceinline__ unsigned short f2bf(float f) {
    unsigned int u = __float_as_uint(f);
    unsigned int r = u + 0x7fffu + ((u >> 16) & 1u);  // RNE
    return (unsigned short)(r >> 16);
}

// ---------------- coarse histogram: bcnt[dst>>8] ----------------
__global__ __launch_bounds__(256) void k_bhist(const int* __restrict__ dst,
                                               int* __restrict__ bcnt, int e) {
    __shared__ int h[NBMAX];
    for (int i = threadIdx.x; i < NBMAX; i += 256) h[i] = 0;
    __syncthreads();
    int base = blockIdx.x * EPB;
    int end = min(base + EPB, e);
    for (int i = base + threadIdx.x; i < end; i += 256) atomicAdd(&h[dst[i] >> 8], 1);
    __syncthreads();
    for (int i = threadIdx.x; i < NBMAX; i += 256) {
        int c = h[i];
        if (c) atomicAdd(&bcnt[i], c);
    }
}

// ---------------- bucket scan: bbase (exclusive) + gcur init ----------------
__global__ __launch_bounds__(512) void k_bscan(const int* __restrict__ bcnt,
                                               int* __restrict__ bbase,
                                               int* __restrict__ gcur, int nb, int e) {
    __shared__ int sh[512];
    int v = (threadIdx.x < nb) ? bcnt[threadIdx.x] : 0;
    sh[threadIdx.x] = v;
    __syncthreads();
    for (int off = 1; off < 512; off <<= 1) {
        int t = (threadIdx.x >= off) ? sh[threadIdx.x - off] : 0;
        __syncthreads();
        sh[threadIdx.x] += t;
        __syncthreads();
    }
    int excl = sh[threadIdx.x] - v;
    if (threadIdx.x < nb) {
        bbase[threadIdx.x] = excl;
        gcur[threadIdx.x] = excl;
    }
    if (threadIdx.x == 0) bbase[nb] = e;
}

// ---------------- coarse scatter: coarse[p] = (src, dst), bucketed ----------------
__global__ __launch_bounds__(256) void k_scatterA(const int* __restrict__ src,
                                                  const int* __restrict__ dst,
                                                  int* __restrict__ gcur,
                                                  uint2* __restrict__ coarse, int e) {
    __shared__ int cur[NBMAX];
    for (int i = threadIdx.x; i < NBMAX; i += 256) cur[i] = 0;
    __syncthreads();
    int base = blockIdx.x * EPB;
    int end = min(base + EPB, e);
    for (int i = base + threadIdx.x; i < end; i += 256) atomicAdd(&cur[dst[i] >> 8], 1);
    __syncthreads();
    for (int i = threadIdx.x; i < NBMAX; i += 256) {
        int c = cur[i];
        cur[i] = c ? atomicAdd(&gcur[i], c) : 0;
    }
    __syncthreads();
    for (int i = base + threadIdx.x; i < end; i += 256) {
        int d = dst[i];
        int p = atomicAdd(&cur[d >> 8], 1);
        coarse[p] = make_uint2((unsigned)src[i], (unsigned)d);
    }
}

// ---------------- per-bucket degree count (LDS atomics) ----------------
__global__ __launch_bounds__(256) void k_bdeg(const uint2* __restrict__ coarse,
                                              const int* __restrict__ bbase,
                                              int* __restrict__ deg, int n) {
    __shared__ int ld[256];
    ld[threadIdx.x] = 1;  // self-loop
    __syncthreads();
    int b = blockIdx.x;
    int s = bbase[b], t = bbase[b + 1];
    for (int i = s + threadIdx.x; i < t; i += 256) atomicAdd(&ld[coarse[i].y & 255], 1);
    __syncthreads();
    int node = b * 256 + threadIdx.x;
    if (node < n) deg[node] = ld[threadIdx.x];
}

__global__ void k_dinv(const int* __restrict__ deg, float* __restrict__ dinv, int n) {
    int i = blockIdx.x * blockDim.x + threadIdx.x;
    if (i < n) dinv[i] = rsqrtf((float)deg[i]);
}

// ---------------- exclusive scan of (deg-1) -> row_start ----------------
__global__ __launch_bounds__(256) void k_scan_a(const int* __restrict__ deg, int* __restrict__ csum, int n) {
    int base = blockIdx.x * CHUNK;
    int s = 0;
    for (int k = threadIdx.x; k < CHUNK; k += 256) {
        int idx = base + k;
        if (idx < n) s += deg[idx] - 1;
    }
    __shared__ int red[256];
    red[threadIdx.x] = s;
    __syncthreads();
    for (int off = 128; off > 0; off >>= 1) {
        if (threadIdx.x < off) red[threadIdx.x] += red[threadIdx.x + off];
        __syncthreads();
    }
    if (threadIdx.x == 0) csum[blockIdx.x] = red[0];
}

__global__ __launch_bounds__(128) void k_scan_b(int* __restrict__ csum, int nch) {
    __shared__ int sh[128];
    int v = (threadIdx.x < nch) ? csum[threadIdx.x] : 0;
    sh[threadIdx.x] = v;
    __syncthreads();
    for (int off = 1; off < 128; off <<= 1) {
        int t = (threadIdx.x >= off) ? sh[threadIdx.x - off] : 0;
        __syncthreads();
        sh[threadIdx.x] += t;
        __syncthreads();
    }
    if (threadIdx.x < nch) csum[threadIdx.x] = sh[threadIdx.x] - v;  // exclusive
}

__global__ __launch_bounds__(256) void k_scan_c(const int* __restrict__ deg, const int* __restrict__ csum,
                                                int* __restrict__ row_start, int n) {
    int base = blockIdx.x * CHUNK + threadIdx.x * 4;
    int v[4];
    int s = 0;
    #pragma unroll
    for (int k = 0; k < 4; ++k) {
        v[k] = (base + k < n) ? (deg[base + k] - 1) : 0;
        s += v[k];
    }
    __shared__ int tsum[256];
    tsum[threadIdx.x] = s;
    __syncthreads();
    for (int off = 1; off < 256; off <<= 1) {
        int t = (threadIdx.x >= off) ? tsum[threadIdx.x - off] : 0;
        __syncthreads();
        tsum[threadIdx.x] += t;
        __syncthreads();
    }
    int run = (threadIdx.x ? tsum[threadIdx.x - 1] : 0) + csum[blockIdx.x];
    #pragma unroll
    for (int k = 0; k < 4; ++k) {
        if (base + k < n) {
            row_start[base + k] = run;
            run += v[k];
        }
    }
}

// ---------------- per-bucket fine bin: ebuf[row_start..] = src (LDS cursors) ----------------
__global__ __launch_bounds__(256) void k_bbin(const uint2* __restrict__ coarse,
                                              const int* __restrict__ bbase,
                                              const int* __restrict__ row_start,
                                              int* __restrict__ ebuf, int n) {
    __shared__ int cur[256];
    int b = blockIdx.x;
    int node = b * 256 + threadIdx.x;
    cur[threadIdx.x] = (node < n) ? row_start[node] : 0;
    __syncthreads();
    int s = bbase[b], t = bbase[b + 1];
    for (int i = s + threadIdx.x; i < t; i += 256) {
        uint2 p = coarse[i];
        int pos = atomicAdd(&cur[p.y & 255], 1);
        ebuf[pos] = (int)p.x;
    }
}

// ---------------- hs = bf16((x @ W) * dinv[row]) ----------------
__global__ __launch_bounds__(256) void k_gemm(
    const float* __restrict__ x, const float* __restrict__ W,
    const float* __restrict__ dinv, unsigned short* __restrict__ hs, int n) {
    __shared__ float Ws[FDIM * FDIM];  // 64 KB, row-major [k][c]
    {
        const float4* W4 = (const float4*)W;
        float4* Wl = (float4*)Ws;
        for (int i = threadIdx.x; i < FDIM * FDIM / 4; i += 256) Wl[i] = W4[i];
    }
    __syncthreads();

    const int cg = threadIdx.x & 15;
    const int rg = threadIdx.x >> 4;
    const int row0 = blockIdx.x * 128 + rg * 8;
    const float4* Ws4 = (const float4*)Ws;

    const float4* xp[8];
    #pragma unroll
    for (int r = 0; r < 8; ++r) {
        int rc = row0 + r;
        if (rc >= n) rc = n - 1;
        xp[r] = (const float4*)(x + (size_t)rc * FDIM);
    }

    float4 acc[8][2];
    #pragma unroll
    for (int r = 0; r < 8; ++r) {
        acc[r][0] = make_float4(0.f, 0.f, 0.f, 0.f);
        acc[r][1] = make_float4(0.f, 0.f, 0.f, 0.f);
    }

    #pragma unroll 2
    for (int k4 = 0; k4 < FDIM / 4; ++k4) {
        float4 xv[8];
        #pragma unroll
        for (int r = 0; r < 8; ++r) xv[r] = xp[r][k4];
        #pragma unroll
        for (int kk = 0; kk < 4; ++kk) {
            float4 w0 = Ws4[(k4 * 4 + kk) * 32 + cg];
            float4 w1 = Ws4[(k4 * 4 + kk) * 32 + 16 + cg];
            #pragma unroll
            for (int r = 0; r < 8; ++r) {
                float xs = (kk == 0) ? xv[r].x : (kk == 1) ? xv[r].y : (kk == 2) ? xv[r].z : xv[r].w;
                acc[r][0].x += xs * w0.x;
                acc[r][0].y += xs * w0.y;
                acc[r][0].z += xs * w0.z;
                acc[r][0].w += xs * w0.w;
                acc[r][1].x += xs * w1.x;
                acc[r][1].y += xs * w1.y;
                acc[r][1].z += xs * w1.z;
                acc[r][1].w += xs * w1.w;
            }
        }
    }

    #pragma unroll
    for (int r = 0; r < 8; ++r) {
        int row = row0 + r;
        if (row >= n) break;
        float s = dinv[row];
        ushort4 p0, p1;
        p0.x = f2bf(acc[r][0].x * s);
        p0.y = f2bf(acc[r][0].y * s);
        p0.z = f2bf(acc[r][0].z * s);
        p0.w = f2bf(acc[r][0].w * s);
        p1.x = f2bf(acc[r][1].x * s);
        p1.y = f2bf(acc[r][1].y * s);
        p1.z = f2bf(acc[r][1].z * s);
        p1.w = f2bf(acc[r][1].w * s);
        *(ushort4*)(hs + (size_t)row * FDIM + cg * 4) = p0;
        *(ushort4*)(hs + (size_t)row * FDIM + 64 + cg * 4) = p1;
    }
}

// ---------------- gather: out[i] = dinv[i]*(hs[i] + sum hs[src]) + b ----------------
__global__ __launch_bounds__(256) void k_gather(
    const unsigned short* __restrict__ hs, const int* __restrict__ ebuf,
    const int* __restrict__ row_start, const int* __restrict__ deg,
    const float* __restrict__ dinv, const float* __restrict__ bias,
    float* __restrict__ out, int n) {
    int i = blockIdx.x * 4 + (threadIdx.x >> 6);
    if (i >= n) return;
    int lane = threadIdx.x & 63;

    int beg = row_start[i];
    int cnt = deg[i] - 1;
    int end = beg + cnt;

    unsigned int u = ((const unsigned int*)(hs + (size_t)i * FDIM))[lane];
    float ax = __uint_as_float(u << 16);
    float ay = __uint_as_float(u & 0xffff0000u);

    int j = beg;
    for (; j + 3 < end; j += 4) {
        int s0 = ebuf[j], s1 = ebuf[j + 1], s2 = ebuf[j + 2], s3 = ebuf[j + 3];
        unsigned int u0 = ((const unsigned int*)(hs + (size_t)s0 * FDIM))[lane];
        unsigned int u1 = ((const unsigned int*)(hs + (size_t)s1 * FDIM))[lane];
        unsigned int u2 = ((const unsigned int*)(hs + (size_t)s2 * FDIM))[lane];
        unsigned int u3 = ((const unsigned int*)(hs + (size_t)s3 * FDIM))[lane];
        ax += __uint_as_float(u0 << 16) + __uint_as_float(u1 << 16)
            + __uint_as_float(u2 << 16) + __uint_as_float(u3 << 16);
        ay += __uint_as_float(u0 & 0xffff0000u) + __uint_as_float(u1 & 0xffff0000u)
            + __uint_as_float(u2 & 0xffff0000u) + __uint_as_float(u3 & 0xffff0000u);
    }
    for (; j < end; ++j) {
        int s0 = ebuf[j];
        unsigned int u0 = ((const unsigned int*)(hs + (size_t)s0 * FDIM))[lane];
        ax += __uint_as_float(u0 << 16);
        ay += __uint_as_float(u0 & 0xffff0000u);
    }

    float sc = dinv[i];
    float2 bb = ((const float2*)bias)[lane];
    float2 r = make_float2(ax * sc + bb.x, ay * sc + bb.y);
    ((float2*)(out + (size_t)i * FDIM))[lane] = r;
}

extern "C" void kernel_launch(void* const* d_in, const int* in_sizes, int n_in,
                              void* d_out, int out_size, void* d_ws, size_t ws_size,
                              hipStream_t stream) {
    const float* x  = (const float*)d_in[0];
    const int*   ei = (const int*)d_in[1];     // [2, E] int32
    const float* W  = (const float*)d_in[2];
    const float* b  = (const float*)d_in[3];

    const int n = in_sizes[0] / FDIM;
    const int e = in_sizes[1] / 2;
    const int* src = ei;
    const int* dst = ei + e;
    float* out = (float*)d_out;

    const int nch = (n + CHUNK - 1) / CHUNK;
    const int nb = (n + 255) >> 8;              // coarse buckets
    const int eblocks = (e + EPB - 1) / EPB;

    char* ws = (char*)d_ws;
    size_t off = 0;
    auto alloc = [&](size_t bytes) {
        char* p = ws + off;
        off += (bytes + 511) & ~(size_t)511;
        return p;
    };
    int*            deg       = (int*)alloc((size_t)n * 4);
    float*          dinv      = (float*)alloc((size_t)n * 4);
    int*            row_start = (int*)alloc((size_t)n * 4);
    int*            csum      = (int*)alloc((size_t)nch * 4);
    int*            bcnt      = (int*)alloc((size_t)NBMAX * 4);
    int*            bbase     = (int*)alloc((size_t)(NBMAX + 1) * 4);
    int*            gcur      = (int*)alloc((size_t)NBMAX * 4);
    uint2*          coarse    = (uint2*)alloc((size_t)e * 8);
    int*            ebuf      = (int*)alloc((size_t)e * 4);
    unsigned short* hs        = (unsigned short*)alloc((size_t)n * FDIM * 2);

    // zero bucket counters (ws is poisoned each call)
    hipMemsetAsync(bcnt, 0, (size_t)NBMAX * 4, stream);

    k_bhist<<<eblocks, 256, 0, stream>>>(dst, bcnt, e);
    k_bscan<<<1, 512, 0, stream>>>(bcnt, bbase, gcur, nb, e);
    k_scatterA<<<eblocks, 256, 0, stream>>>(src, dst, gcur, coarse, e);
    k_bdeg<<<nb, 256, 0, stream>>>(coarse, bbase, deg, n);
    k_dinv<<<(n + 255) / 256, 256, 0, stream>>>(deg, dinv, n);

    k_scan_a<<<nch, 256, 0, stream>>>(deg, csum, n);
    k_scan_b<<<1, 128, 0, stream>>>(csum, nch);
    k_scan_c<<<nch, 256, 0, stream>>>(deg, csum, row_start, n);

    k_gemm<<<(n + 127) / 128, 256, 0, stream>>>(x, W, dinv, hs, n);
    k_bbin<<<nb, 256, 0, stream>>>(coarse, bbase, row_start, ebuf, n);

    {
        int blocks = (n + 3) / 4;
        k_gather<<<blocks, 256, 0, stream>>>(hs, ebuf, row_start, deg, dinv, b, out, n);
    }
}